// Round 2
// baseline (413.771 us; speedup 1.0000x reference)
//
#include <hip/hip_runtime.h>
#include <math.h>

// FCNNSlopeValuationFunction: per-row angle -> zone -> gather dir[row, zone],
// masked by z_1[:,0] != 0.
//
// R1 change: the f64 atan2 (ocml: f64 divide + ~25-term f64 poly, on CDNA4's
// derated FP64 pipe) was ~6x the memory floor. Zone depends only on
// int(phi_degrees), and zone changes only at 16 integer angles
// {9+22k, k=0..11} u {281,303,325,347}. Fast path: f32 atan2f (~1-2 ulp,
// <= ~4 ulp of the reference's correctly-rounded value after the degrees
// multiply, i.e. <= 1.2e-4 deg). Only if phi lands within 0.01 deg of a zone
// boundary (rate ~9e-4) do we recompute with the exact f64 path that passed
// R1 with absmax 0.0. Everywhere else the zone provably matches.
//
// Numerics kept from R1:
//  - degrees = single f32 multiply by f32(180/pi), contraction off.
//  - (90+int(phi))%360, ((pcs+11)/22) floor, %8: exact in f32 small-int range.
//  - no zone boundary at 0/360 or 180, so atan2 sign-wrap ulp issues are
//    harmless (zone 4 on both sides of the wrap).

__device__ __forceinline__ bool is_zone_boundary(int u) {
    // u in [0, 361]
    return (u <= 251 && (u % 22) == 9) ||
           (u >= 281 && u <= 347 && (u % 22) == 17);
}

__global__ __launch_bounds__(256) void slope_zone_kernel(
    const float* __restrict__ z1,
    const float* __restrict__ dir,
    float* __restrict__ out,
    int n)
{
#pragma clang fp contract(off)
    int i = blockIdx.x * blockDim.x + threadIdx.x;
    if (i >= n) return;

    // z_1 row: 16 floats, 64B line. Need cols 0..4.
    const float4* zrow = reinterpret_cast<const float4*>(z1 + (size_t)i * 16);
    float4 a = zrow[0];                       // x=line, y=lx, z=ly, w=rx
    float ry = z1[(size_t)i * 16 + 4];

    float dx = a.w - a.y;                     // rx - lx
    float dy = -(ry - a.z);                   // -(ry - ly)

    // fast path: f32 atan2 (ocml, ~1-2 ulp)
    float phi = atan2f(dy, dx) * 57.29577951308232f;
    if (phi < 0.0f) phi = 360.0f + phi;
    int t = (int)phi;                         // trunc == floor (phi >= 0)

    // boundary-proximity guard: fall back to the exact f64 path (bit-matched
    // the numpy reference in R1) when within 0.01 deg of a zone boundary.
    float fl = (float)t;
    bool near = ((phi - fl)        < 0.01f && is_zone_boundary(t)) ||
                ((fl + 1.0f - phi) < 0.01f && is_zone_boundary(t + 1));
    if (near) {
        float phid = (float)atan2((double)dy, (double)dx) * 57.29577951308232f;
        if (phid < 0.0f) phid = 360.0f + phid;
        t = (int)phid;
    }

    int pcs = (90 + t) % 360;                 // t in [0,360] -> pcs in [0,359]
    int z = (int)(((float)pcs + 11.0f) / 22.0f);
    int zone = z & 7;                         // z in [0,16] -> %8

    float picked = dir[(size_t)i * 8 + zone];
    out[i] = (a.x != 0.0f) ? picked : 0.0f;
}

extern "C" void kernel_launch(void* const* d_in, const int* in_sizes, int n_in,
                              void* d_out, int out_size, void* d_ws, size_t ws_size,
                              hipStream_t stream) {
    const float* z1  = (const float*)d_in[0];   // (B,16) f32
    const float* dir = (const float*)d_in[1];   // (B,8)  f32
    float* out = (float*)d_out;                 // (B,)   f32
    int n = out_size;
    int threads = 256;
    int blocks = (n + threads - 1) / threads;
    hipLaunchKernelGGL(slope_zone_kernel, dim3(blocks), dim3(threads), 0, stream,
                       z1, dir, out, n);
}

// Round 3
// 413.632 us; speedup vs baseline: 1.0003x; 1.0003x over previous
//
#include <hip/hip_runtime.h>
#include <math.h>

// FCNNSlopeValuationFunction: per-row angle -> zone -> pick dir[row, zone],
// masked by z_1[:,0] != 0.
//
// R2 post-mortem: kernel dispatch is <151 us (absent from rocprof top-5; the
// 412 us dur includes ~280 us of per-iter harness restore/poison traffic).
// Kernel ~130 us vs 63 us HBM floor => latency-bound: the dir gather was
// DEPENDENT on the zone (z1 load -> atan2 -> zone -> dir load), two serial
// ~900-cycle HBM phases per thread.
//
// R3 change: dir's 64B lines are fully consumed anyway (2 rows/line, both
// touched), so load the entire 8-float dir row (2x float4) concurrently with
// the z1 loads and select the zone element with a cndmask tree. One memory
// phase, same HBM traffic.
//
// Numerics (bit-matched numpy, absmax 0.0 in R1/R2):
//  - fast path f32 atan2f; exact-f64 fallback only within 0.01 deg of the 16
//    integer zone-boundary angles {9+22k} u {281,303,325,347} (rate ~1e-3).
//  - degrees = single f32 mul by f32(180/pi), contraction off.
//  - small-int float ops ((pcs+11)/22 floor etc.) exact in f32.

__device__ __forceinline__ bool is_zone_boundary(int u) {
    // u in [0, 361]
    return (u <= 251 && (u % 22) == 9) ||
           (u >= 281 && u <= 347 && (u % 22) == 17);
}

__global__ __launch_bounds__(256) void slope_zone_kernel(
    const float* __restrict__ z1,
    const float* __restrict__ dir,
    float* __restrict__ out,
    int n)
{
#pragma clang fp contract(off)
    int i = blockIdx.x * blockDim.x + threadIdx.x;
    if (i >= n) return;

    // Issue ALL loads up front (independent): z1 cols 0..4, full dir row.
    const float4* zrow = reinterpret_cast<const float4*>(z1 + (size_t)i * 16);
    float4 a  = zrow[0];                      // x=line, y=lx, z=ly, w=rx
    float  ry = z1[(size_t)i * 16 + 4];
    const float4* drow = reinterpret_cast<const float4*>(dir + (size_t)i * 8);
    float4 dlo = drow[0];                     // dir[0..3]
    float4 dhi = drow[1];                     // dir[4..7]

    float dx = a.w - a.y;                     // rx - lx
    float dy = -(ry - a.z);                   // -(ry - ly)

    float phi = atan2f(dy, dx) * 57.29577951308232f;
    if (phi < 0.0f) phi = 360.0f + phi;
    int t = (int)phi;                         // trunc == floor (phi >= 0)

    // rare exact-f64 fallback near zone boundaries (bit-matches numpy)
    float fl = (float)t;
    bool near = ((phi - fl)        < 0.01f && is_zone_boundary(t)) ||
                ((fl + 1.0f - phi) < 0.01f && is_zone_boundary(t + 1));
    if (near) {
        float phid = (float)atan2((double)dy, (double)dx) * 57.29577951308232f;
        if (phid < 0.0f) phid = 360.0f + phid;
        t = (int)phid;
    }

    int pcs = (90 + t) % 360;                 // t in [0,360] -> pcs in [0,359]
    int z = (int)(((float)pcs + 11.0f) / 22.0f);
    int zone = z & 7;                         // z in [0,16] -> %8

    // cndmask selection tree, no dependent load
    float s0 = (zone & 1) ? dlo.y : dlo.x;
    float s1 = (zone & 1) ? dlo.w : dlo.z;
    float s2 = (zone & 1) ? dhi.y : dhi.x;
    float s3 = (zone & 1) ? dhi.w : dhi.z;
    float t0 = (zone & 2) ? s1 : s0;
    float t1 = (zone & 2) ? s3 : s2;
    float picked = (zone & 4) ? t1 : t0;

    out[i] = (a.x != 0.0f) ? picked : 0.0f;
}

extern "C" void kernel_launch(void* const* d_in, const int* in_sizes, int n_in,
                              void* d_out, int out_size, void* d_ws, size_t ws_size,
                              hipStream_t stream) {
    const float* z1  = (const float*)d_in[0];   // (B,16) f32
    const float* dir = (const float*)d_in[1];   // (B,8)  f32
    float* out = (float*)d_out;                 // (B,)   f32
    int n = out_size;
    int threads = 256;
    int blocks = (n + threads - 1) / threads;
    hipLaunchKernelGGL(slope_zone_kernel, dim3(blocks), dim3(threads), 0, stream,
                       z1, dir, out, n);
}